// Round 3
// baseline (291.171 us; speedup 1.0000x reference)
//
#include <hip/hip_runtime.h>

#define TLEN 100
#define ECN  100
#define CA1N 100
#define CA3N 100
#define BSZ  4096
#define ACTN 2
#define BT   16     // batch rows per block (= MFMA M)

typedef short bf16x8 __attribute__((ext_vector_type(8)));
typedef float f32x4  __attribute__((ext_vector_type(4)));

__device__ __forceinline__ unsigned short f2bf(float f){ // round-half-up bf16
  union { float f; unsigned int u; } c; c.f = f;
  return (unsigned short)((c.u + 0x8000u) >> 16);
}
__device__ __forceinline__ float fsigm(float x){ // 1/(1+exp(-x)), fast rcp
  float e = __expf(-x);
  return __builtin_amdgcn_rcpf(1.0f + e);
}

// Barrier with LDS-only drain (R2 win, -13%): correctness needs only
// ca1b/ec3b LDS ordering across waves; global stores / drive loads float.
#define BAR_LGKM() asm volatile("s_waitcnt lgkmcnt(0)\n\ts_barrier" ::: "memory")

// ---- kernel 0: drive[t][j] = sum_k exp(-((t-c_k)/5)^2/2) * Wca3ca1[k][j] ----
__global__ void drive_kernel(const float* __restrict__ Wca3ca1, float* __restrict__ drive){
  __shared__ float ca3row[CA3N];
  const int t = blockIdx.x, tid = threadIdx.x;
  if (tid < CA3N){
    float c = (float)tid * (100.0f / 99.0f);   // linspace(0,100,100)
    float d = ((float)t - c) * 0.2f;           // /SIGMA=5
    ca3row[tid] = __expf(-0.5f * d * d);
  }
  __syncthreads();
  if (tid < CA1N){
    float acc = 0.f;
    for (int k = 0; k < CA3N; ++k) acc = fmaf(ca3row[k], Wca3ca1[k*CA1N + tid], acc);
    drive[t*CA1N + tid] = acc;
  }
}

// frag-linear bf16 A-shadow: element (m,k) lives at
//   ks*512 + (m + 16*((k>>3)&3))*8 + (k&7)   [shorts], ks = k>>5
// so a wave's ds_read_b128 at (ks*1024 + lane*16) bytes is lane-contiguous.
//
// R3 structure: 4 waves (256 thr), wave w owns col-tiles {2w, 2w+1}
// (wave 3's tile 7 is dead). Each wave reads A once and does 8 MFMAs:
// LDS read traffic/phase 28KB -> 16KB, 1 wave/SIMD (no lockstep VALU
// doubling), 4-wave barriers instead of 8.

__global__ __launch_bounds__(256, 1)
void rnn_kernel(const int*   __restrict__ cue_train,
                const float* __restrict__ ec3_last,
                const float* __restrict__ ec5_last,
                const float* __restrict__ cueL,
                const float* __restrict__ cueR,
                const float* __restrict__ Wec3ca1,
                const float* __restrict__ Wca1ec5,
                const float* __restrict__ Wca1act,
                const float* __restrict__ ca1bias,
                const float* __restrict__ drive,
                float*       __restrict__ out)
{
  __shared__ __align__(16) unsigned short ec3b[4 * 64 * 8]; // frag-linear bf16 ec3
  __shared__ __align__(16) unsigned short ca1b[4 * 64 * 8]; // frag-linear bf16 ca1
  __shared__ __align__(16) float ca1f[BT * 132];            // final ca1 (epilogue)
  __shared__ signed char cueT[TLEN * BT];                   // cue transposed [t][r]

  const int tid = threadIdx.x;   // 0..255
  const int b0  = blockIdx.x * BT;

  float* out_act = out;
  float* out_his = out + (size_t)BSZ * ACTN;
  float* out_e3  = out_his + (size_t)TLEN * BSZ * CA1N;
  float* out_e5  = out_e3 + (size_t)BSZ * ECN;
  float* out_c1  = out_e5 + (size_t)BSZ * ECN;

  // --- zero frag shadows (pad rows k>=100 must stay 0 forever) ---
  for (int idx = tid; idx < 4 * 64 * 8; idx += 256){ ec3b[idx] = 0; ca1b[idx] = 0; }
  // --- stage cue ---
  for (int idx = tid; idx < BT * TLEN; idx += 256){
    int t = idx >> 4, r = idx & 15;
    cueT[idx] = (signed char)cue_train[(size_t)(b0 + r) * TLEN + t];
  }

  const int lane  = tid & 63;
  const int wv    = tid >> 6;          // wave id 0..3
  const int col16 = lane & 15;
  const int q     = lane >> 4;         // quad (rows q*4..q*4+3)
  const int tl0   = wv * 2;            // first col-tile
  const int tl1   = wv * 2 + 1;        // second col-tile (dead for wv=3)
  const int col0  = tl0 * 16 + col16;
  const int col1  = tl1 * 16 + col16;
  const bool ok0  = (col0 < CA1N);
  const bool ok1  = (col1 < CA1N);
  const bool live1 = (tl1 < 7);        // wave-uniform: tile1 has any live cols
  const int col0c = ok0 ? col0 : 0;
  const int col1c = ok1 ? col1 : 0;

  // per-lane frag-write bases (shorts)
  const int ab0 = (col0 >> 5) * 512 + ((col0 >> 3) & 3) * 128 + (col0 & 7) + q * 32;
  const int ab1 = (col1 >> 5) * 512 + ((col1 >> 3) & 3) * 128 + (col1 & 7) + q * 32;

  // --- B-fragments in registers (bf16 weights), two tiles per wave ---
  bf16x8 b1[2][4], b2[2][4];           // [tile][ks]; B[k][n]: k=ks*32+q*8+jj
  #pragma unroll
  for (int ks = 0; ks < 4; ++ks){
    #pragma unroll
    for (int jj = 0; jj < 8; ++jj){
      int k = ks * 32 + q * 8 + jj;
      float w10 = 0.f, w20 = 0.f, w11 = 0.f, w21 = 0.f;
      if (k < ECN){
        if (ok0){ w10 = Wec3ca1[k * CA1N + col0]; w20 = Wca1ec5[k * ECN + col0]; }
        if (ok1){ w11 = Wec3ca1[k * CA1N + col1]; w21 = Wca1ec5[k * ECN + col1]; }
      }
      b1[0][ks][jj] = (short)f2bf(w10);
      b2[0][ks][jj] = (short)f2bf(w20);
      b1[1][ks][jj] = (short)f2bf(w11);
      b2[1][ks][jj] = (short)f2bf(w21);
    }
  }
  const float bias0 = ok0 ? ca1bias[col0] : 0.f;
  const float bias1 = ok1 ? ca1bias[col1] : 0.f;
  const float cL0 = ok0 ? cueL[col0] : 0.f;
  const float cR0 = ok0 ? cueR[col0] : 0.f;
  const float cL1 = ok1 ? cueL[col1] : 0.f;
  const float cR1 = ok1 ? cueR[col1] : 0.f;

  __syncthreads();  // frag zero complete before state writes

  // --- fp32 state in registers: [tile][i], lane owns (r=q*4+i, colX) ---
  float ec3v[2][4], ec5v[2][4], c1[2][4];
  #pragma unroll
  for (int i = 0; i < 4; ++i){
    int r = q * 4 + i;
    float v30 = ok0 ? ec3_last[(size_t)(b0 + r) * ECN + col0] : 0.f;
    float v50 = ok0 ? ec5_last[(size_t)(b0 + r) * ECN + col0] : 0.f;
    float v31 = ok1 ? ec3_last[(size_t)(b0 + r) * ECN + col1] : 0.f;
    float v51 = ok1 ? ec5_last[(size_t)(b0 + r) * ECN + col1] : 0.f;
    ec3v[0][i] = v30; ec5v[0][i] = v50; c1[0][i] = 0.f;
    ec3v[1][i] = v31; ec5v[1][i] = v51; c1[1][i] = 0.f;
    if (ok0) ec3b[ab0 + i * 8] = f2bf(v30);
    if (ok1) ec3b[ab1 + i * 8] = f2bf(v31);
  }
  __syncthreads();

  // running pointers
  const float* dp = drive + CA1N;      // next step's drive row
  float dv0 = drive[col0c];
  float dv1 = drive[col1c];
  float* hp0 = out_his + (size_t)(b0 + q * 4) * CA1N + col0c;   // += BSZ*CA1N/step
  float* hp1 = out_his + (size_t)(b0 + q * 4) * CA1N + col1c;

  const bf16x8* fe3 = (const bf16x8*)ec3b;   // chunk ks at index ks*64+lane
  const bf16x8* fc1 = (const bf16x8*)ca1b;

  for (int t = 0; t < TLEN; ++t){
    int cu4 = *(const int*)(cueT + t * BT + q * 4);   // 4 cue bytes (rows q*4..)

    // ---- phase 1: z = ec3 @ W1 ; ca1 = relu(dv*(1+sig(z)) - bias) ----
    {
      bf16x8 a0 = fe3[  0 + lane];
      bf16x8 a1 = fe3[ 64 + lane];
      bf16x8 a2 = fe3[128 + lane];
      bf16x8 a3 = fe3[192 + lane];
      f32x4 aA = {0.f,0.f,0.f,0.f}, aB = {0.f,0.f,0.f,0.f};
      aA = __builtin_amdgcn_mfma_f32_16x16x32_bf16(a0, b1[0][0], aA, 0, 0, 0);
      aB = __builtin_amdgcn_mfma_f32_16x16x32_bf16(a1, b1[0][1], aB, 0, 0, 0);
      aA = __builtin_amdgcn_mfma_f32_16x16x32_bf16(a2, b1[0][2], aA, 0, 0, 0);
      aB = __builtin_amdgcn_mfma_f32_16x16x32_bf16(a3, b1[0][3], aB, 0, 0, 0);
      f32x4 z0 = aA + aB;
      float dmb0 = dv0 - bias0;
      #pragma unroll
      for (int i = 0; i < 4; ++i){
        float v = fmaxf(fmaf(dv0, fsigm(z0[i]), dmb0), 0.f);
        c1[0][i] = v;
        if (ok0) ca1b[ab0 + i * 8] = f2bf(v);
      }
      if (live1){
        f32x4 cA = {0.f,0.f,0.f,0.f}, cB = {0.f,0.f,0.f,0.f};
        cA = __builtin_amdgcn_mfma_f32_16x16x32_bf16(a0, b1[1][0], cA, 0, 0, 0);
        cB = __builtin_amdgcn_mfma_f32_16x16x32_bf16(a1, b1[1][1], cB, 0, 0, 0);
        cA = __builtin_amdgcn_mfma_f32_16x16x32_bf16(a2, b1[1][2], cA, 0, 0, 0);
        cB = __builtin_amdgcn_mfma_f32_16x16x32_bf16(a3, b1[1][3], cB, 0, 0, 0);
        f32x4 z1 = cA + cB;
        float dmb1 = dv1 - bias1;
        #pragma unroll
        for (int i = 0; i < 4; ++i){
          float v = fmaxf(fmaf(dv1, fsigm(z1[i]), dmb1), 0.f);
          c1[1][i] = v;
          if (ok1) ca1b[ab1 + i * 8] = f2bf(v);
        }
      }
    }
    BAR_LGKM();

    // out_his stores after the barrier: no vmcnt drain at loop barriers,
    // they stay in flight under phase-2 compute.
    if (ok0){
      hp0[0 * CA1N] = c1[0][0];
      hp0[1 * CA1N] = c1[0][1];
      hp0[2 * CA1N] = c1[0][2];
      hp0[3 * CA1N] = c1[0][3];
    }
    if (live1 && ok1){
      hp1[0 * CA1N] = c1[1][0];
      hp1[1 * CA1N] = c1[1][1];
      hp1[2 * CA1N] = c1[1][2];
      hp1[3 * CA1N] = c1[1][3];
    }
    hp0 += (size_t)BSZ * CA1N;
    hp1 += (size_t)BSZ * CA1N;

    // prefetch next step's drive values (float across the phase-2 barrier)
    float nv0 = 0.f, nv1 = 0.f;
    if (t + 1 < TLEN){ nv0 = dp[col0c]; nv1 = dp[col1c]; }
    dp += CA1N;

    // ---- phase 2: z2 = ca1 @ W2 ; ec5/ec3 register update ----
    {
      bf16x8 a0 = fc1[  0 + lane];
      bf16x8 a1 = fc1[ 64 + lane];
      bf16x8 a2 = fc1[128 + lane];
      bf16x8 a3 = fc1[192 + lane];
      f32x4 aA = {0.f,0.f,0.f,0.f}, aB = {0.f,0.f,0.f,0.f};
      aA = __builtin_amdgcn_mfma_f32_16x16x32_bf16(a0, b2[0][0], aA, 0, 0, 0);
      aB = __builtin_amdgcn_mfma_f32_16x16x32_bf16(a1, b2[0][1], aB, 0, 0, 0);
      aA = __builtin_amdgcn_mfma_f32_16x16x32_bf16(a2, b2[0][2], aA, 0, 0, 0);
      aB = __builtin_amdgcn_mfma_f32_16x16x32_bf16(a3, b2[0][3], aB, 0, 0, 0);
      f32x4 z2 = aA + aB;
      #pragma unroll
      for (int i = 0; i < 4; ++i){
        float x  = ec5v[0][i] + z2[i];
        float e5 = fmaf(0.3f, fsigm(fmaf(4.0f, x, -1.2f)), 0.69f);
        ec5v[0][i] = e5;
        int cu = (cu4 >> (8 * i)) & 0xff;               // -1 -> 0xff
        float sns = (cu == 1) ? cL0 : ((cu == 0xff) ? cR0 : 0.0f);
        float e3 = fmaf(e5, ec3v[0][i], sns);
        ec3v[0][i] = e3;
        if (ok0) ec3b[ab0 + i * 8] = f2bf(e3);
      }
      if (live1){
        f32x4 cA = {0.f,0.f,0.f,0.f}, cB = {0.f,0.f,0.f,0.f};
        cA = __builtin_amdgcn_mfma_f32_16x16x32_bf16(a0, b2[1][0], cA, 0, 0, 0);
        cB = __builtin_amdgcn_mfma_f32_16x16x32_bf16(a1, b2[1][1], cB, 0, 0, 0);
        cA = __builtin_amdgcn_mfma_f32_16x16x32_bf16(a2, b2[1][2], cA, 0, 0, 0);
        cB = __builtin_amdgcn_mfma_f32_16x16x32_bf16(a3, b2[1][3], cB, 0, 0, 0);
        f32x4 z21 = cA + cB;
        #pragma unroll
        for (int i = 0; i < 4; ++i){
          float x  = ec5v[1][i] + z21[i];
          float e5 = fmaf(0.3f, fsigm(fmaf(4.0f, x, -1.2f)), 0.69f);
          ec5v[1][i] = e5;
          int cu = (cu4 >> (8 * i)) & 0xff;
          float sns = (cu == 1) ? cL1 : ((cu == 0xff) ? cR1 : 0.0f);
          float e3 = fmaf(e5, ec3v[1][i], sns);
          ec3v[1][i] = e3;
          if (ok1) ec3b[ab1 + i * 8] = f2bf(e3);
        }
      }
    }
    BAR_LGKM();
    dv0 = nv0; dv1 = nv1;
  }

  // ---- epilogue: dump final states from registers ----
  #pragma unroll
  for (int i = 0; i < 4; ++i){
    int r = q * 4 + i;
    if (ok0){
      size_t g = (size_t)(b0 + r) * ECN + col0;
      out_e3[g] = ec3v[0][i];
      out_e5[g] = ec5v[0][i];
      out_c1[g] = c1[0][i];
      ca1f[r * 132 + col0] = c1[0][i];
    }
    if (live1 && ok1){
      size_t g = (size_t)(b0 + r) * ECN + col1;
      out_e3[g] = ec3v[1][i];
      out_e5[g] = ec5v[1][i];
      out_c1[g] = c1[1][i];
      ca1f[r * 132 + col1] = c1[1][i];
    }
  }
  __syncthreads();

  // actCell = ca1_final @ Wca1act
  if (tid < BT * ACTN){
    int r = tid >> 1, a = tid & 1;
    float acc = 0.f;
    for (int jj = 0; jj < CA1N; ++jj)
      acc = fmaf(ca1f[r * 132 + jj], Wca1act[jj * ACTN + a], acc);
    out_act[(size_t)(b0 + r) * ACTN + a] = acc;
  }
}

extern "C" void kernel_launch(void* const* d_in, const int* in_sizes, int n_in,
                              void* d_out, int out_size, void* d_ws, size_t ws_size,
                              hipStream_t stream) {
  (void)in_sizes; (void)n_in; (void)out_size; (void)ws_size;
  const int*   cue_train = (const int*)  d_in[1];
  const float* ec3_last  = (const float*)d_in[2];
  const float* ec5_last  = (const float*)d_in[3];
  const float* cueL      = (const float*)d_in[5];
  const float* cueR      = (const float*)d_in[6];
  const float* Wec3ca1   = (const float*)d_in[7];
  const float* Wca3ca1   = (const float*)d_in[8];
  const float* Wca1ec5   = (const float*)d_in[9];
  const float* Wca1act   = (const float*)d_in[10];
  const float* ca1bias   = (const float*)d_in[11];
  float* out   = (float*)d_out;
  float* drive = (float*)d_ws;   // 100*100 fp32 = 40 KB scratch

  drive_kernel<<<TLEN, 128, 0, stream>>>(Wca3ca1, drive);
  rnn_kernel<<<BSZ / BT, 256, 0, stream>>>(cue_train, ec3_last, ec5_last,
                                           cueL, cueR, Wec3ca1, Wca1ec5,
                                           Wca1act, ca1bias, drive, out);
}